// Round 6
// baseline (65406.323 us; speedup 1.0000x reference)
//
#include <hip/hip_runtime.h>
#include <math.h>

// Problem constants
#define B 2048
#define T 128
#define H 512
#define NC 3
#define NO 5
#define G3H 1536
#define BHD ((size_t)B * H)   // dwords per packed state slot

typedef _Float16 half8 __attribute__((ext_vector_type(8)));
typedef float float4v __attribute__((ext_vector_type(4)));
typedef unsigned int uint32;
typedef unsigned int uint4v __attribute__((ext_vector_type(4)));

#define LO_SCALE 1024.0f
#define INV_LO (1.0f / 1024.0f)
#define F16_MIN_NORM 6.103515625e-05f

__device__ __forceinline__ float sigmoidf_(float x) { return 1.0f / (1.0f + __expf(-x)); }

__device__ __forceinline__ void split_f16(float a, _Float16* hi, _Float16* lo) {
    _Float16 h = (_Float16)a;
    if (fabsf(a) < F16_MIN_NORM) h = (_Float16)0.0f;
    *hi = h;
    *lo = (_Float16)((a - (float)h) * LO_SCALE);
}
__device__ __forceinline__ uint32 pack_f(float a) {
    _Float16 h, l; split_f16(a, &h, &l);
    unsigned short hu, lu;
    __builtin_memcpy(&hu, &h, 2); __builtin_memcpy(&lu, &l, 2);
    return (uint32)hu | ((uint32)lu << 16);
}
__device__ __forceinline__ float unpack_f(uint32 d) {
    unsigned short hu = (unsigned short)(d & 0xffff), lu = (unsigned short)(d >> 16);
    _Float16 h, l;
    __builtin_memcpy(&h, &hu, 2); __builtin_memcpy(&l, &lu, 2);
    return (float)h + (float)l * INV_LO;
}
// element (row,k) of a 512-col matrix stored at row*512 + swzk(row,k)
__device__ __forceinline__ int swzk(int row, int k) {
    return (k & ~63) | ((((k >> 3) & 7) ^ (row & 7)) << 3) | (k & 7);
}

// agent-scope (cross-XCD-visible) state I/O — compiler emits proper sc bits
__device__ __forceinline__ uint32 ldA_sc(const uint32* p) {
    return __hip_atomic_load(p, __ATOMIC_RELAXED, __HIP_MEMORY_SCOPE_AGENT);
}
__device__ __forceinline__ void stA_sc(uint32* p, uint32 v) {
    __hip_atomic_store(p, v, __ATOMIC_RELAXED, __HIP_MEMORY_SCOPE_AGENT);
}

// async 16B global->LDS, L2-cacheable (weights only)
__device__ __forceinline__ void stage16(const _Float16* gp, _Float16* lp) {
    __builtin_amdgcn_global_load_lds(
        (const __attribute__((address_space(1))) unsigned int*)gp,
        (__attribute__((address_space(3))) unsigned int*)lp,
        16, 0, 0);
}

// ---------------- prep kernels ----------------
__global__ void conv3_kernel(const float* __restrict__ w1, const float* __restrict__ w2,
                             const float* __restrict__ w3,
                             _Float16* o1h, _Float16* o1l, _Float16* o2h, _Float16* o2l,
                             _Float16* o3h, _Float16* o3l) {
    int i = blockIdx.x * 256 + threadIdx.x;
    if (i < G3H * H) {
        const int r = i >> 9, k = i & 511;
        const size_t d = (size_t)r * H + swzk(r, k);
        split_f16(w1[i], &o1h[d], &o1l[d]);
        split_f16(w2[i], &o2h[d], &o2l[d]);
        split_f16(w3[i], &o3h[d], &o3l[d]);
    }
}

__global__ void prep_kernel(const float* __restrict__ h01, const float* __restrict__ h02,
                            uint32* __restrict__ hp1, uint32* __restrict__ hp2) {
    int i = blockIdx.x * 256 + threadIdx.x;
    if (i < B * H) {
        const int r = i >> 9, k = i & 511;
        const size_t d = (size_t)r * H + swzk(r, k);
        hp1[d] = pack_f(h01[i]);
        hp2[d] = pack_f(h02[i]);
    }
}

// ---------------- MFMA tile compute (verified R5 structure) ----------------
__device__ __forceinline__ void compute_tile(
    const _Float16* sAh, const _Float16* sAl,
    const _Float16* sWh, const _Float16* sWl,
    int wm, int wn, int ln, int qd, int sN,
    float4v (&accH)[4][2][2], float4v (&accL)[4][2][2])
{
    #pragma unroll
    for (int ks = 0; ks < 2; ++ks) {
        const int c = ks * 4 + qd;
        half8 afh[2], afl[2];
        #pragma unroll
        for (int mt = 0; mt < 2; ++mt) {
            const int row = wm * 32 + mt * 16 + ln;
            const int ai = row * 64 + ((c ^ (row & 7)) << 3);
            afh[mt] = *(const half8*)&sAh[ai];
            afl[mt] = *(const half8*)&sAl[ai];
        }
        #pragma unroll
        for (int g = 0; g < 3; ++g) {
            const int s = (g < 2) ? g : sN;
            #pragma unroll
            for (int nt = 0; nt < 2; ++nt) {
                const int nr = wn * 32 + nt * 16 + ln;
                const int wi = (g * 64 + nr) * 64 + ((c ^ (nr & 7)) << 3);
                half8 bh = *(const half8*)&sWh[wi];
                half8 bl = *(const half8*)&sWl[wi];
                #pragma unroll
                for (int mt = 0; mt < 2; ++mt) {
                    accH[s][mt][nt] = __builtin_amdgcn_mfma_f32_16x16x32_f16(afh[mt], bh, accH[s][mt][nt], 0, 0, 0);
                    accL[s][mt][nt] = __builtin_amdgcn_mfma_f32_16x16x32_f16(afh[mt], bl, accL[s][mt][nt], 0, 0, 0);
                    accL[s][mt][nt] = __builtin_amdgcn_mfma_f32_16x16x32_f16(afl[mt], bh, accL[s][mt][nt], 0, 0, 0);
                }
            }
        }
    }
}

// ---------------- persistent full-rollout kernel ----------------
// 256 blocks x 256 threads, 1 block/CU. bid&7 -> n-tile (XCD-local W slice),
// bid>>3 -> m-tile. 2 relaxed grid barriers/step; NO cache-flushing fences.
__global__ __launch_bounds__(256, 1) void gru_persist_kernel(
    const _Float16* __restrict__ wh1h, const _Float16* __restrict__ wh1l,
    const _Float16* __restrict__ wi2h, const _Float16* __restrict__ wi2l,
    const _Float16* __restrict__ wh2h, const _Float16* __restrict__ wh2l,
    const float* __restrict__ W_ih1, const float* __restrict__ W_out,
    const float* __restrict__ b_out,
    const float* __restrict__ b_ih1, const float* __restrict__ b_hh1,
    const float* __restrict__ b_ih2, const float* __restrict__ b_hh2,
    const float* __restrict__ cmds, const float* __restrict__ y0,
    const float* __restrict__ h01, const float* __restrict__ h02,
    uint32* __restrict__ hp1, uint32* __restrict__ hp2,   // packed, 2 slots each
    float* __restrict__ out,
    uint32* __restrict__ bar)
{
    __shared__ _Float16 sAh[2][4096], sAl[2][4096];     // 32 KB
    __shared__ _Float16 sWh[2][12288], sWl[2][12288];   // 96 KB
    __shared__ float sX[64 * 8];
    __shared__ float sWi1[3][8][64];
    __shared__ float sBi1[3][64], sBh1[3][64], sBi2[3][64], sBh2[3][64];
    __shared__ float sWout[5 * 512];
    __shared__ float sBout[8];

    const int tid = threadIdx.x;
    const int wv = tid >> 6, lane = tid & 63;
    const int wm = wv >> 1, wn = wv & 1;
    const int ln = lane & 15, qd = lane >> 4;
    const int bid = blockIdx.x;
    const int n0 = (bid & 7) * 64;
    const int m0 = (bid >> 3) * 64;

    // ---- one-time LDS fills ----
    for (int i = tid; i < 3 * 64 * 8; i += 256) {
        const int g = i >> 9, rem = i & 511, n = rem >> 3, k = rem & 7;
        sWi1[g][k][n] = W_ih1[(g * H + n0 + n) * 8 + k];
    }
    if (tid < 192) {
        const int g = tid >> 6, n = tid & 63;
        sBi1[g][n] = b_ih1[g * H + n0 + n];
        sBh1[g][n] = b_hh1[g * H + n0 + n];
        sBi2[g][n] = b_ih2[g * H + n0 + n];
        sBh2[g][n] = b_hh2[g * H + n0 + n];
    }
    for (int i = tid; i < 5 * 512; i += 256) sWout[i] = W_out[i];
    if (tid < 5) sBout[tid] = b_out[tid];
    __syncthreads();

    // ---- block-owned h_prev slices in registers ----
    float hprev1[2][2][4], hprev2[2][2][4];
    #pragma unroll
    for (int mt = 0; mt < 2; ++mt)
        #pragma unroll
        for (int nt = 0; nt < 2; ++nt)
            #pragma unroll
            for (int r = 0; r < 4; ++r) {
                const int m = m0 + wm * 32 + mt * 16 + qd * 4 + r;
                const int gn = n0 + wn * 32 + nt * 16 + ln;
                hprev1[mt][nt][r] = h01[(size_t)m * H + gn];
                hprev2[mt][nt][r] = h02[(size_t)m * H + gn];
            }

    uint32 bt = 0;
    auto gbar = [&]() {
        __syncthreads();   // drains vmcnt(0): sc1 stores globally visible
        bt += 256;
        if (tid == 0) {
            __hip_atomic_fetch_add(bar, 1u, __ATOMIC_RELAXED, __HIP_MEMORY_SCOPE_AGENT);
            while (__hip_atomic_load(bar, __ATOMIC_RELAXED, __HIP_MEMORY_SCOPE_AGENT) < bt)
                __builtin_amdgcn_s_sleep(2);
        }
        __syncthreads();
    };

    // ---- staging helpers ----
    struct AR { uint32 d[16]; };
    auto loadA = [&](const uint32* src, int k0) {
        AR a;
        #pragma unroll
        for (int u2 = 0; u2 < 2; ++u2) {
            const int u = tid * 2 + u2;          // slot id: 64 rows x 8 slots
            const int row = u >> 3, s = u & 7;   // positional copy (layout-preserving)
            const uint32* p = src + (size_t)(m0 + row) * H + k0 + s * 8;
            #pragma unroll
            for (int j = 0; j < 8; ++j) a.d[u2 * 8 + j] = ldA_sc(p + j);
        }
        return a;
    };
    auto writeA = [&](const AR& a, _Float16* bAh, _Float16* bAl) {
        #pragma unroll
        for (int u2 = 0; u2 < 2; ++u2) {
            const int u = tid * 2 + u2;
            const int row = u >> 3, s = u & 7;
            uint4v hi, lo;
            #pragma unroll
            for (int j = 0; j < 4; ++j) {
                const uint32 d0 = a.d[u2 * 8 + 2 * j], d1 = a.d[u2 * 8 + 2 * j + 1];
                hi[j] = (d0 & 0xffffu) | (d1 << 16);
                lo[j] = (d0 >> 16) | (d1 & 0xffff0000u);
            }
            const int idx = row * 64 + s * 8;
            *(uint4v*)&bAh[idx] = hi;
            *(uint4v*)&bAl[idx] = lo;
        }
    };
    auto stageW = [&](const _Float16* Whp, const _Float16* Wlp, int k0, int buf) {
        #pragma unroll
        for (int j = 0; j < 6; ++j) {
            const int cid = wv * 384 + j * 64 + lane;
            const int gg = cid >> 9, rem = cid & 511;
            const int nr = rem >> 3, kc = rem & 7;
            const size_t off = (size_t)(gg * H + n0 + nr) * H + k0 + kc * 8;
            stage16(Whp + off, &sWh[buf][(wv * 384 + j * 64) * 8]);
            stage16(Wlp + off, &sWl[buf][(wv * 384 + j * 64) * 8]);
        }
    };

    float4v accH[4][2][2], accL[4][2][2];
    auto zero_acc = [&]() {
        #pragma unroll
        for (int s = 0; s < 4; ++s)
            #pragma unroll
            for (int a = 0; a < 2; ++a)
                #pragma unroll
                for (int b = 0; b < 2; ++b) { accH[s][a][b] = (float4v)(0.f); accL[s][a][b] = (float4v)(0.f); }
    };

    struct Seg { const uint32* A; const _Float16* Wh; const _Float16* Wl; int sN; };
    auto run_segs = [&](const Seg* segs, int nseg) {
        AR a0 = loadA(segs[0].A, 0);
        stageW(segs[0].Wh, segs[0].Wl, 0, 0);
        writeA(a0, sAh[0], sAl[0]);
        const int total = nseg * 8;
        #pragma unroll 1
        for (int gt = 0; gt < total; ++gt) {
            const int buf = gt & 1;
            __syncthreads();   // tile gt's W lds-loads + A ds_writes complete
            if (gt + 1 < total) {
                const Seg& s = segs[(gt + 1) >> 3];
                const int k0 = ((gt + 1) & 7) * 64;
                stageW(s.Wh, s.Wl, k0, buf ^ 1);
                AR an = loadA(s.A, k0);
                compute_tile(sAh[buf], sAl[buf], sWh[buf], sWl[buf],
                             wm, wn, ln, qd, segs[gt >> 3].sN, accH, accL);
                writeA(an, sAh[buf ^ 1], sAl[buf ^ 1]);
            } else {
                compute_tile(sAh[buf], sAl[buf], sWh[buf], sWl[buf],
                             wm, wn, ln, qd, segs[gt >> 3].sN, accH, accL);
            }
        }
    };

    // y = h2_row . Wout^T + bout (rows m0..m0+63); p=tid&3 splits K.
    auto compute_y = [&](const uint32* h2p, float* y5) {
        const int r = tid >> 2, p = tid & 3;
        const int row = m0 + r;
        float a0 = 0, a1 = 0, a2 = 0, a3 = 0, a4 = 0;
        #pragma unroll
        for (int g = 0; g < 2; ++g) {
            const int grp = p * 2 + g;          // 64-element group
            #pragma unroll
            for (int s = 0; s < 8; ++s) {
                const uint32* src = h2p + (size_t)row * H + grp * 64 + s * 8;
                const int kb = grp * 64 + ((s ^ (row & 7)) << 3);
                #pragma unroll
                for (int j = 0; j < 8; ++j) {
                    const float hv = unpack_f(ldA_sc(src + j));
                    const int k = kb + j;
                    a0 = fmaf(hv, sWout[k], a0);
                    a1 = fmaf(hv, sWout[512 + k], a1);
                    a2 = fmaf(hv, sWout[1024 + k], a2);
                    a3 = fmaf(hv, sWout[1536 + k], a3);
                    a4 = fmaf(hv, sWout[2048 + k], a4);
                }
            }
        }
        a0 += __shfl_xor(a0, 1, 64); a0 += __shfl_xor(a0, 2, 64);
        a1 += __shfl_xor(a1, 1, 64); a1 += __shfl_xor(a1, 2, 64);
        a2 += __shfl_xor(a2, 1, 64); a2 += __shfl_xor(a2, 2, 64);
        a3 += __shfl_xor(a3, 1, 64); a3 += __shfl_xor(a3, 2, 64);
        a4 += __shfl_xor(a4, 1, 64); a4 += __shfl_xor(a4, 2, 64);
        y5[0] = a0 + sBout[0]; y5[1] = a1 + sBout[1]; y5[2] = a2 + sBout[2];
        y5[3] = a3 + sBout[3]; y5[4] = a4 + sBout[4];
    };

    int si = 0;
    #pragma unroll 1
    for (int t = 0; t < T; ++t) {
        uint32* h1p = hp1 + (size_t)si * BHD;
        uint32* h2p = hp2 + (size_t)si * BHD;
        uint32* h1n = hp1 + (size_t)(si ^ 1) * BHD;
        uint32* h2n = hp2 + (size_t)(si ^ 1) * BHD;

        // ---- x_t = [y_{t-1}, cmd_t]; also emit out[:, t-1, :] ----
        if (t == 0) {
            if (tid < 64) {
                #pragma unroll
                for (int o2 = 0; o2 < NO; ++o2)
                    sX[tid * 8 + o2] = y0[(size_t)(m0 + tid) * NO + o2];
            }
        } else {
            float y5[5];
            compute_y(h2p, y5);
            const int r = tid >> 2, p = tid & 3;
            if (p == 0) {
                #pragma unroll
                for (int o2 = 0; o2 < NO; ++o2) sX[r * 8 + o2] = y5[o2];
                if (n0 == 0) {
                    #pragma unroll
                    for (int o2 = 0; o2 < NO; ++o2)
                        out[(size_t)(m0 + r) * (T * NO) + (size_t)(t - 1) * NO + o2] = y5[o2];
                }
            }
        }
        if (tid < 64) {
            #pragma unroll
            for (int c = 0; c < NC; ++c)
                sX[tid * 8 + NO + c] = cmds[(size_t)t * B * NC + (size_t)(m0 + tid) * NC + c];
        }

        // ================= phase A: layer 1 =================
        zero_acc();
        {
            Seg segs[1] = { { h1p, wh1h, wh1l, 3 } };
            run_segs(segs, 1);
        }
        #pragma unroll
        for (int nt = 0; nt < 2; ++nt) {
            const int gnl = wn * 32 + nt * 16 + ln;
            const int gn = n0 + gnl;
            #pragma unroll
            for (int mt = 0; mt < 2; ++mt) {
                #pragma unroll
                for (int r = 0; r < 4; ++r) {
                    const int mloc = wm * 32 + mt * 16 + qd * 4 + r;
                    const int m = m0 + mloc;
                    float giR = sBi1[0][gnl], giZ = sBi1[1][gnl], giN = sBi1[2][gnl];
                    #pragma unroll
                    for (int k = 0; k < 8; ++k) {
                        const float xv = sX[mloc * 8 + k];
                        giR = fmaf(xv, sWi1[0][k][gnl], giR);
                        giZ = fmaf(xv, sWi1[1][k][gnl], giZ);
                        giN = fmaf(xv, sWi1[2][k][gnl], giN);
                    }
                    const float gR = giR + sBh1[0][gnl] + accH[0][mt][nt][r] + accL[0][mt][nt][r] * INV_LO;
                    const float gZ = giZ + sBh1[1][gnl] + accH[1][mt][nt][r] + accL[1][mt][nt][r] * INV_LO;
                    const float gNh = sBh1[2][gnl] + accH[3][mt][nt][r] + accL[3][mt][nt][r] * INV_LO;
                    const float R = sigmoidf_(gR), Z = sigmoidf_(gZ);
                    const float N = tanhf(fmaf(R, gNh, giN));
                    const float hv = (1.f - Z) * N + Z * hprev1[mt][nt][r];
                    hprev1[mt][nt][r] = hv;
                    stA_sc(h1n + (size_t)m * H + swzk(m, gn), pack_f(hv));
                }
            }
        }
        gbar();

        // ================= phase B: layer 2 =================
        zero_acc();
        {
            Seg segs[2] = { { h1n, wi2h, wi2l, 2 }, { h2p, wh2h, wh2l, 3 } };
            run_segs(segs, 2);
        }
        #pragma unroll
        for (int nt = 0; nt < 2; ++nt) {
            const int gnl = wn * 32 + nt * 16 + ln;
            const int gn = n0 + gnl;
            #pragma unroll
            for (int mt = 0; mt < 2; ++mt) {
                #pragma unroll
                for (int r = 0; r < 4; ++r) {
                    const int m = m0 + wm * 32 + mt * 16 + qd * 4 + r;
                    const float gR = sBi2[0][gnl] + sBh2[0][gnl]
                        + accH[0][mt][nt][r] + accL[0][mt][nt][r] * INV_LO;
                    const float gZ = sBi2[1][gnl] + sBh2[1][gnl]
                        + accH[1][mt][nt][r] + accL[1][mt][nt][r] * INV_LO;
                    const float gNi = sBi2[2][gnl] + accH[2][mt][nt][r] + accL[2][mt][nt][r] * INV_LO;
                    const float gNh = sBh2[2][gnl] + accH[3][mt][nt][r] + accL[3][mt][nt][r] * INV_LO;
                    const float R = sigmoidf_(gR), Z = sigmoidf_(gZ);
                    const float N = tanhf(fmaf(R, gNh, gNi));
                    const float hv = (1.f - Z) * N + Z * hprev2[mt][nt][r];
                    hprev2[mt][nt][r] = hv;
                    stA_sc(h2n + (size_t)m * H + swzk(m, gn), pack_f(hv));
                }
            }
        }
        gbar();
        si ^= 1;
    }

    // final y_{T-1}
    {
        float y5[5];
        compute_y(hp2 + (size_t)si * BHD, y5);
        const int r = tid >> 2, p = tid & 3;
        if (p == 0 && n0 == 0) {
            #pragma unroll
            for (int o2 = 0; o2 < NO; ++o2)
                out[(size_t)(m0 + r) * (T * NO) + (size_t)(T - 1) * NO + o2] = y5[o2];
        }
    }
}

extern "C" void kernel_launch(void* const* d_in, const int* in_sizes, int n_in,
                              void* d_out, int out_size, void* d_ws, size_t ws_size,
                              hipStream_t stream) {
    (void)in_sizes; (void)n_in; (void)out_size; (void)ws_size;
    const float* cmds  = (const float*)d_in[1];
    const float* y0    = (const float*)d_in[2];
    const float* h01   = (const float*)d_in[3];
    const float* h02   = (const float*)d_in[4];
    const float* W_ih1 = (const float*)d_in[5];
    const float* W_hh1 = (const float*)d_in[6];
    const float* b_ih1 = (const float*)d_in[7];
    const float* b_hh1 = (const float*)d_in[8];
    const float* W_ih2 = (const float*)d_in[9];
    const float* W_hh2 = (const float*)d_in[10];
    const float* b_ih2 = (const float*)d_in[11];
    const float* b_hh2 = (const float*)d_in[12];
    const float* W_out = (const float*)d_in[13];
    const float* b_out = (const float*)d_in[14];
    float* out = (float*)d_out;

    // ---- workspace (~26.2 MB) ----
    char* ws = (char*)d_ws;
    size_t o = 0;
    const size_t WSZ = (size_t)G3H * H * sizeof(_Float16);
    _Float16* wh1h = (_Float16*)(ws + o); o += WSZ;
    _Float16* wh1l = (_Float16*)(ws + o); o += WSZ;
    _Float16* wi2h = (_Float16*)(ws + o); o += WSZ;
    _Float16* wi2l = (_Float16*)(ws + o); o += WSZ;
    _Float16* wh2h = (_Float16*)(ws + o); o += WSZ;
    _Float16* wh2l = (_Float16*)(ws + o); o += WSZ;
    uint32* hp1 = (uint32*)(ws + o); o += 2 * BHD * 4;
    uint32* hp2 = (uint32*)(ws + o); o += 2 * BHD * 4;
    uint32* bar = (uint32*)(ws + o); o += 256;

    hipMemsetAsync(bar, 0, sizeof(uint32), stream);
    conv3_kernel<<<(G3H * H + 255) / 256, 256, 0, stream>>>(
        W_hh1, W_ih2, W_hh2, wh1h, wh1l, wi2h, wi2l, wh2h, wh2l);
    prep_kernel<<<(B * H + 255) / 256, 256, 0, stream>>>(h01, h02, hp1, hp2);

    gru_persist_kernel<<<256, 256, 0, stream>>>(
        wh1h, wh1l, wi2h, wi2l, wh2h, wh2l,
        W_ih1, W_out, b_out,
        b_ih1, b_hh1, b_ih2, b_hh2,
        cmds, y0, h01, h02,
        hp1, hp2, out, bar);
}

// Round 7
// 8593.825 us; speedup vs baseline: 7.6109x; 7.6109x over previous
//
#include <hip/hip_runtime.h>
#include <math.h>

// Problem constants
#define B 2048
#define T 128
#define H 512
#define NC 3
#define NO 5
#define G3H 1536
#define BHE ((size_t)B * H)

typedef _Float16 half8 __attribute__((ext_vector_type(8)));
typedef float float4v __attribute__((ext_vector_type(4)));

#define LO_SCALE 1024.0f
#define INV_LO (1.0f / 1024.0f)
#define F16_MIN_NORM 6.103515625e-05f

__device__ __forceinline__ float sigmoidf_(float x) { return 1.0f / (1.0f + __expf(-x)); }

// Split fp32 -> (hi, lo*1024) f16 pair; hi zeroed in subnormal range (flush safety).
__device__ __forceinline__ void split_f16(float a, _Float16* hi, _Float16* lo) {
    _Float16 h = (_Float16)a;
    if (fabsf(a) < F16_MIN_NORM) h = (_Float16)0.0f;
    *hi = h;
    *lo = (_Float16)((a - (float)h) * LO_SCALE);
}

// element (row,k) of a 512-col matrix stored at row*512 + swzk(row,k):
// 16B chunk c=(k>>3)&7 lives in slot c ^ (row&7)  (LDS-conflict-free fragments)
__device__ __forceinline__ int swzk(int row, int k) {
    return (k & ~63) | ((((k >> 3) & 7) ^ (row & 7)) << 3) | (k & 7);
}
__device__ __forceinline__ size_t hidx(int row, int k) {
    return (size_t)row * H + swzk(row, k);
}

// async 16B global->LDS (wave-uniform LDS base; lane lands at base + lane*16B)
__device__ __forceinline__ void stage16(const _Float16* gp, _Float16* lp) {
    __builtin_amdgcn_global_load_lds(
        (const __attribute__((address_space(1))) unsigned int*)gp,
        (__attribute__((address_space(3))) unsigned int*)lp,
        16, 0, 0);
}

// ---------------- prep kernels (once per launch) ----------------
__global__ void conv3_kernel(const float* __restrict__ w1, const float* __restrict__ w2,
                             const float* __restrict__ w3,
                             _Float16* o1h, _Float16* o1l, _Float16* o2h, _Float16* o2l,
                             _Float16* o3h, _Float16* o3l) {
    int i = blockIdx.x * 256 + threadIdx.x;
    if (i < G3H * H) {
        const int r = i >> 9, k = i & 511;
        const size_t d = (size_t)r * H + swzk(r, k);
        split_f16(w1[i], &o1h[d], &o1l[d]);
        split_f16(w2[i], &o2h[d], &o2l[d]);
        split_f16(w3[i], &o3h[d], &o3l[d]);
    }
}

__global__ void prep_kernel(const float* __restrict__ h01, const float* __restrict__ h02,
                            _Float16* h1h, _Float16* h1l, _Float16* h2h, _Float16* h2l) {
    int i = blockIdx.x * 256 + threadIdx.x;
    if (i < B * H) {
        const int r = i >> 9, k = i & 511;
        const size_t d = (size_t)r * H + swzk(r, k);
        split_f16(h01[i], &h1h[d], &h1l[d]);
        split_f16(h02[i], &h2h[d], &h2l[d]);
    }
}

// ---------------- staging: one 64x64 K-tile (A 16KB + 3-gate W 48KB) ----------------
// 512 threads: A = 512 chunks (1/thread/component), W = 1536 chunks (3/thread/comp)
__device__ __forceinline__ void stage_tile(
    const _Float16* __restrict__ Ahp, const _Float16* __restrict__ Alp,
    const _Float16* __restrict__ Whp, const _Float16* __restrict__ Wlp,
    int m0, int n0, int k0, int tid, int wv,
    _Float16* sAh, _Float16* sAl, _Float16* sWh, _Float16* sWl)
{
    {
        const int row = tid >> 3, kc = tid & 7;
        const size_t off = (size_t)(m0 + row) * H + k0 + kc * 8;
        stage16(Ahp + off, &sAh[(wv * 64) * 8]);
        stage16(Alp + off, &sAl[(wv * 64) * 8]);
    }
    #pragma unroll
    for (int j = 0; j < 3; ++j) {
        const int cid = j * 512 + tid;
        const int gg = cid >> 9, rem = cid & 511;
        const int nr = rem >> 3, kc = rem & 7;
        const size_t off = (size_t)(gg * H + n0 + nr) * H + k0 + kc * 8;
        stage16(Whp + off, &sWh[(j * 512 + wv * 64) * 8]);
        stage16(Wlp + off, &sWl[(j * 512 + wv * 64) * 8]);
    }
}

// ---------------- one 64x64x64 tile of 3-gate split-f16 MFMA ----------------
// 8 waves: wm=wv>>1 (m-quarter, 16 rows), wn=wv&1 (n-half, 32 cols/gate)
__device__ __forceinline__ void compute_tile(
    const _Float16* sAh, const _Float16* sAl,
    const _Float16* sWh, const _Float16* sWl,
    int wm, int wn, int ln, int qd, int sN,
    float4v (&accH)[4][2], float4v (&accL)[4][2])
{
    #pragma unroll
    for (int ks = 0; ks < 2; ++ks) {
        const int c = ks * 4 + qd;
        const int row = wm * 16 + ln;
        const int ai = row * 64 + ((c ^ (row & 7)) << 3);
        half8 afh = *(const half8*)&sAh[ai];
        half8 afl = *(const half8*)&sAl[ai];
        #pragma unroll
        for (int g = 0; g < 3; ++g) {
            const int s = (g < 2) ? g : sN;
            #pragma unroll
            for (int nt = 0; nt < 2; ++nt) {
                const int nr = wn * 32 + nt * 16 + ln;
                const int wi = (g * 64 + nr) * 64 + ((c ^ (nr & 7)) << 3);
                half8 bh = *(const half8*)&sWh[wi];
                half8 bl = *(const half8*)&sWl[wi];
                accH[s][nt] = __builtin_amdgcn_mfma_f32_16x16x32_f16(afh, bh, accH[s][nt], 0, 0, 0);
                accL[s][nt] = __builtin_amdgcn_mfma_f32_16x16x32_f16(afh, bl, accL[s][nt], 0, 0, 0);
                accL[s][nt] = __builtin_amdgcn_mfma_f32_16x16x32_f16(afl, bh, accL[s][nt], 0, 0, 0);
            }
        }
    }
}

// ---------------- layer-1 GRU step (+ fused y_{t-1} projection) ----------------
// grid 256 x 512 thr (8 waves = 2/SIMD). bid&7 -> n-tile (XCD-local W slice).
__global__ __launch_bounds__(512, 1) void gru1_kernel(
    const _Float16* __restrict__ Ah, const _Float16* __restrict__ Al,    // h1 prev swz
    const _Float16* __restrict__ Wh, const _Float16* __restrict__ Wl,    // wh1 swz
    const _Float16* __restrict__ h2ph, const _Float16* __restrict__ h2pl,// h2 prev swz
    const float* __restrict__ Wout, const float* __restrict__ bout,
    const float* __restrict__ y0, const float* __restrict__ cmd_t,
    const float* __restrict__ W_ih1,
    const float* __restrict__ b_ih1, const float* __restrict__ b_hh1,
    _Float16* __restrict__ hnh, _Float16* __restrict__ hnl,
    float* __restrict__ out, int t)
{
    __shared__ _Float16 sAh[2][4096], sAl[2][4096];     // 32 KB
    __shared__ _Float16 sWh[2][12288], sWl[2][12288];   // 96 KB
    __shared__ float sX[64 * 8];
    __shared__ float sWi1[3][8][64];
    __shared__ float sBi1[3][64], sBh1[3][64];

    const int tid = threadIdx.x;
    const int wv = tid >> 6, lane = tid & 63;
    const int wm = wv >> 1, wn = wv & 1;
    const int ln = lane & 15, qd = lane >> 4;
    const int n0 = (blockIdx.x & 7) * 64;
    const int m0 = (blockIdx.x >> 3) * 64;

    // one-time LDS fills (consumed after K-loop syncs)
    for (int i = tid; i < 3 * 64 * 8; i += 512) {
        const int g = i >> 9, rem = i & 511, n = rem >> 3, k = rem & 7;
        sWi1[g][k][n] = W_ih1[(g * H + n0 + n) * 8 + k];
    }
    if (tid < 192) {
        const int g = tid >> 6, n = tid & 63;
        sBi1[g][n] = b_ih1[g * H + n0 + n];
        sBh1[g][n] = b_hh1[g * H + n0 + n];
    }

    float4v accH[4][2], accL[4][2];
    #pragma unroll
    for (int s = 0; s < 4; ++s)
        #pragma unroll
        for (int nt = 0; nt < 2; ++nt) { accH[s][nt] = (float4v)(0.f); accL[s][nt] = (float4v)(0.f); }

    // kick off tile 0 (async), then overlap the y-projection with its flight
    stage_tile(Ah, Al, Wh, Wl, m0, n0, 0, tid, wv, sAh[0], sAl[0], sWh[0], sWl[0]);

    // ---- y_{t-1} = h2_prev . Wout^T + bout (this block's 64 rows) ----
    const int yr = tid >> 3, yp = tid & 7;   // row, K-octant
    if (t == 0) {
        if (tid < 64) {
            #pragma unroll
            for (int o2 = 0; o2 < NO; ++o2)
                sX[tid * 8 + o2] = y0[(size_t)(m0 + tid) * NO + o2];
        }
    } else {
        const int row = m0 + yr;
        float a5[NO] = {0.f, 0.f, 0.f, 0.f, 0.f};
        #pragma unroll
        for (int s = 0; s < 8; ++s) {
            const size_t base = (size_t)row * H + yp * 64 + s * 8;
            half8 hh8 = *(const half8*)(h2ph + base);
            half8 hl8 = *(const half8*)(h2pl + base);
            const int kb = yp * 64 + ((s ^ (row & 7)) << 3);
            #pragma unroll
            for (int j4 = 0; j4 < 2; ++j4) {
                float4 wv4[NO];
                #pragma unroll
                for (int o2 = 0; o2 < NO; ++o2)
                    wv4[o2] = *(const float4*)(Wout + (size_t)o2 * H + kb + j4 * 4);
                #pragma unroll
                for (int jj = 0; jj < 4; ++jj) {
                    const int j = j4 * 4 + jj;
                    const float hv = (float)hh8[j] + (float)hl8[j] * INV_LO;
                    a5[0] = fmaf(hv, ((const float*)&wv4[0])[jj], a5[0]);
                    a5[1] = fmaf(hv, ((const float*)&wv4[1])[jj], a5[1]);
                    a5[2] = fmaf(hv, ((const float*)&wv4[2])[jj], a5[2]);
                    a5[3] = fmaf(hv, ((const float*)&wv4[3])[jj], a5[3]);
                    a5[4] = fmaf(hv, ((const float*)&wv4[4])[jj], a5[4]);
                }
            }
        }
        #pragma unroll
        for (int off = 1; off < 8; off <<= 1)
            #pragma unroll
            for (int o2 = 0; o2 < NO; ++o2) a5[o2] += __shfl_xor(a5[o2], off, 64);
        if (yp == 0) {
            #pragma unroll
            for (int o2 = 0; o2 < NO; ++o2) {
                const float y = a5[o2] + bout[o2];
                sX[yr * 8 + o2] = y;
                if (n0 == 0)
                    out[(size_t)(m0 + yr) * (T * NO) + (size_t)(t - 1) * NO + o2] = y;
            }
        }
    }
    if (tid < 64) {
        #pragma unroll
        for (int c = 0; c < NC; ++c)
            sX[tid * 8 + NO + c] = cmd_t[(size_t)(m0 + tid) * NC + c];
    }

    // ---- K-loop: gh = h1_prev @ W_hh1^T (8 tiles), n-gate -> set 3 ----
    for (int it = 0; it < 8; ++it) {
        const int buf = it & 1;
        __syncthreads();
        if (it + 1 < 8)
            stage_tile(Ah, Al, Wh, Wl, m0, n0, (it + 1) * 64, tid, wv,
                       sAh[buf ^ 1], sAl[buf ^ 1], sWh[buf ^ 1], sWl[buf ^ 1]);
        compute_tile(sAh[buf], sAl[buf], sWh[buf], sWl[buf], wm, wn, ln, qd, 3, accH, accL);
    }

    // ---- epilogue: fp32 input path (K=8) + gates + blend ----
    #pragma unroll
    for (int nt = 0; nt < 2; ++nt) {
        const int gnl = wn * 32 + nt * 16 + ln;
        const int gn = n0 + gnl;
        #pragma unroll
        for (int r = 0; r < 4; ++r) {
            const int mloc = wm * 16 + qd * 4 + r;
            const int m = m0 + mloc;
            float giR = sBi1[0][gnl], giZ = sBi1[1][gnl], giN = sBi1[2][gnl];
            #pragma unroll
            for (int k = 0; k < 8; ++k) {
                const float xv = sX[mloc * 8 + k];
                giR = fmaf(xv, sWi1[0][k][gnl], giR);
                giZ = fmaf(xv, sWi1[1][k][gnl], giZ);
                giN = fmaf(xv, sWi1[2][k][gnl], giN);
            }
            const float gR = giR + sBh1[0][gnl] + accH[0][nt][r] + accL[0][nt][r] * INV_LO;
            const float gZ = giZ + sBh1[1][gnl] + accH[1][nt][r] + accL[1][nt][r] * INV_LO;
            const float gNh = sBh1[2][gnl] + accH[3][nt][r] + accL[3][nt][r] * INV_LO;
            const float R = sigmoidf_(gR), Z = sigmoidf_(gZ);
            const float N = tanhf(fmaf(R, gNh, giN));
            const size_t idx = hidx(m, gn);
            const float hp = (float)Ah[idx] + (float)Al[idx] * INV_LO;
            const float hv = (1.f - Z) * N + Z * hp;
            split_f16(hv, &hnh[idx], &hnl[idx]);
        }
    }
}

// ---------------- layer-2 GRU step ----------------
__global__ __launch_bounds__(512, 1) void gru2_kernel(
    const _Float16* __restrict__ Aih, const _Float16* __restrict__ Ail,  // h1 cur swz
    const _Float16* __restrict__ Wih, const _Float16* __restrict__ Wil,  // wi2 swz
    const _Float16* __restrict__ Ahh, const _Float16* __restrict__ Ahl,  // h2 prev swz
    const _Float16* __restrict__ Whh, const _Float16* __restrict__ Whl,  // wh2 swz
    const float* __restrict__ b_i, const float* __restrict__ b_h,
    _Float16* __restrict__ hnh, _Float16* __restrict__ hnl)
{
    __shared__ _Float16 sAh[2][4096], sAl[2][4096];
    __shared__ _Float16 sWh[2][12288], sWl[2][12288];
    __shared__ float sBi[3][64], sBh[3][64];

    const int tid = threadIdx.x;
    const int wv = tid >> 6, lane = tid & 63;
    const int wm = wv >> 1, wn = wv & 1;
    const int ln = lane & 15, qd = lane >> 4;
    const int n0 = (blockIdx.x & 7) * 64;
    const int m0 = (blockIdx.x >> 3) * 64;

    if (tid < 192) {
        const int g = tid >> 6, n = tid & 63;
        sBi[g][n] = b_i[g * H + n0 + n];
        sBh[g][n] = b_h[g * H + n0 + n];
    }

    float4v accH[4][2], accL[4][2];
    #pragma unroll
    for (int s = 0; s < 4; ++s)
        #pragma unroll
        for (int nt = 0; nt < 2; ++nt) { accH[s][nt] = (float4v)(0.f); accL[s][nt] = (float4v)(0.f); }

    stage_tile(Aih, Ail, Wih, Wil, m0, n0, 0, tid, wv, sAh[0], sAl[0], sWh[0], sWl[0]);
    for (int it = 0; it < 16; ++it) {
        const int buf = it & 1;
        __syncthreads();
        if (it + 1 < 16) {
            const int k0 = ((it + 1) & 7) * 64;
            if (it + 1 < 8)
                stage_tile(Aih, Ail, Wih, Wil, m0, n0, k0, tid, wv,
                           sAh[buf ^ 1], sAl[buf ^ 1], sWh[buf ^ 1], sWl[buf ^ 1]);
            else
                stage_tile(Ahh, Ahl, Whh, Whl, m0, n0, k0, tid, wv,
                           sAh[buf ^ 1], sAl[buf ^ 1], sWh[buf ^ 1], sWl[buf ^ 1]);
        }
        compute_tile(sAh[buf], sAl[buf], sWh[buf], sWl[buf],
                     wm, wn, ln, qd, (it < 8) ? 2 : 3, accH, accL);
    }

    #pragma unroll
    for (int nt = 0; nt < 2; ++nt) {
        const int gnl = wn * 32 + nt * 16 + ln;
        const int gn = n0 + gnl;
        #pragma unroll
        for (int r = 0; r < 4; ++r) {
            const int m = m0 + wm * 16 + qd * 4 + r;
            const float gR = sBi[0][gnl] + sBh[0][gnl] + accH[0][nt][r] + accL[0][nt][r] * INV_LO;
            const float gZ = sBi[1][gnl] + sBh[1][gnl] + accH[1][nt][r] + accL[1][nt][r] * INV_LO;
            const float gNi = sBi[2][gnl] + accH[2][nt][r] + accL[2][nt][r] * INV_LO;
            const float gNh = sBh[2][gnl] + accH[3][nt][r] + accL[3][nt][r] * INV_LO;
            const float R = sigmoidf_(gR), Z = sigmoidf_(gZ);
            const float N = tanhf(fmaf(R, gNh, gNi));
            const size_t idx = hidx(m, gn);
            const float hp = (float)Ahh[idx] + (float)Ahl[idx] * INV_LO;
            const float hv = (1.f - Z) * N + Z * hp;
            split_f16(hv, &hnh[idx], &hnl[idx]);
        }
    }
}

// ---------------- final-step output projection ----------------
__global__ __launch_bounds__(256) void yout_final_kernel(
    const _Float16* __restrict__ h2h, const _Float16* __restrict__ h2l,
    const float* __restrict__ Wout, const float* __restrict__ bout,
    float* __restrict__ out)
{
    const int wv = threadIdx.x >> 6, lane = threadIdx.x & 63;
    const int b = blockIdx.x * 4 + wv;
    const size_t hb = (size_t)b * H + lane * 8;
    half8 hh = *(const half8*)(h2h + hb);
    half8 hl = *(const half8*)(h2l + hb);
    const int tl = lane >> 3, cw = lane & 7;
    const int kbase = tl * 64 + ((cw ^ (b & 7)) << 3);
    float hv[8];
    #pragma unroll
    for (int j = 0; j < 8; ++j) hv[j] = (float)hh[j] + (float)hl[j] * INV_LO;
    float acc[NO];
    #pragma unroll
    for (int o = 0; o < NO; ++o) {
        acc[o] = 0.f;
        const float* w = Wout + (size_t)o * H + kbase;
        #pragma unroll
        for (int j = 0; j < 8; ++j) acc[o] = fmaf(hv[j], w[j], acc[o]);
    }
    #pragma unroll
    for (int off = 32; off > 0; off >>= 1)
        #pragma unroll
        for (int o = 0; o < NO; ++o) acc[o] += __shfl_down(acc[o], off, 64);
    if (lane == 0) {
        #pragma unroll
        for (int o = 0; o < NO; ++o)
            out[(size_t)b * (T * NO) + (size_t)(T - 1) * NO + o] = acc[o] + bout[o];
    }
}

extern "C" void kernel_launch(void* const* d_in, const int* in_sizes, int n_in,
                              void* d_out, int out_size, void* d_ws, size_t ws_size,
                              hipStream_t stream) {
    (void)in_sizes; (void)n_in; (void)out_size; (void)ws_size;
    const float* cmds  = (const float*)d_in[1];
    const float* y0    = (const float*)d_in[2];
    const float* h01   = (const float*)d_in[3];
    const float* h02   = (const float*)d_in[4];
    const float* W_ih1 = (const float*)d_in[5];
    const float* W_hh1 = (const float*)d_in[6];
    const float* b_ih1 = (const float*)d_in[7];
    const float* b_hh1 = (const float*)d_in[8];
    const float* W_ih2 = (const float*)d_in[9];
    const float* W_hh2 = (const float*)d_in[10];
    const float* b_ih2 = (const float*)d_in[11];
    const float* b_hh2 = (const float*)d_in[12];
    const float* W_out = (const float*)d_in[13];
    const float* b_out = (const float*)d_in[14];
    float* out = (float*)d_out;

    // ---- workspace (~25.5 MB) ----
    char* ws = (char*)d_ws;
    size_t o = 0;
    const size_t WSZ = (size_t)G3H * H * sizeof(_Float16);
    _Float16* wh1h = (_Float16*)(ws + o); o += WSZ;
    _Float16* wh1l = (_Float16*)(ws + o); o += WSZ;
    _Float16* wi2h = (_Float16*)(ws + o); o += WSZ;
    _Float16* wi2l = (_Float16*)(ws + o); o += WSZ;
    _Float16* wh2h = (_Float16*)(ws + o); o += WSZ;
    _Float16* wh2l = (_Float16*)(ws + o); o += WSZ;
    _Float16 *h1h[2], *h1l[2], *h2h[2], *h2l[2];
    for (int i = 0; i < 2; ++i) { h1h[i] = (_Float16*)(ws + o); o += BHE * 2; }
    for (int i = 0; i < 2; ++i) { h1l[i] = (_Float16*)(ws + o); o += BHE * 2; }
    for (int i = 0; i < 2; ++i) { h2h[i] = (_Float16*)(ws + o); o += BHE * 2; }
    for (int i = 0; i < 2; ++i) { h2l[i] = (_Float16*)(ws + o); o += BHE * 2; }

    conv3_kernel<<<(G3H * H + 255) / 256, 256, 0, stream>>>(
        W_hh1, W_ih2, W_hh2, wh1h, wh1l, wi2h, wi2l, wh2h, wh2l);
    prep_kernel<<<(B * H + 255) / 256, 256, 0, stream>>>(
        h01, h02, h1h[0], h1l[0], h2h[0], h2l[0]);

    for (int t = 0; t < T; ++t) {
        const int si = t & 1, so = si ^ 1;

        gru1_kernel<<<256, 512, 0, stream>>>(
            h1h[si], h1l[si], wh1h, wh1l,
            h2h[si], h2l[si], W_out, b_out,
            y0, cmds + (size_t)t * B * NC,
            W_ih1, b_ih1, b_hh1,
            h1h[so], h1l[so],
            out, t);

        gru2_kernel<<<256, 512, 0, stream>>>(
            h1h[so], h1l[so], wi2h, wi2l,
            h2h[si], h2l[si], wh2h, wh2l,
            b_ih2, b_hh2,
            h2h[so], h2l[so]);
    }

    // final y_{T-1}: T even -> final h2 in slot 0
    yout_final_kernel<<<B / 4, 256, 0, stream>>>(
        h2h[0], h2l[0], W_out, b_out, out);
}